// Round 2
// baseline (231.379 us; speedup 1.0000x reference)
//
#include <hip/hip_runtime.h>

#define LVAL 2048
#define KNB 30
#define NPOS 66
#define EDGE_IN 416
#define NOUT 128
#define NWF (13 * 8 * 64 * 8)   // 425984 bf16 weight elements
#define NRES (4 * LVAL)         // 8192 residues

typedef __bf16 bf16x8 __attribute__((ext_vector_type(8)));
typedef float f32x4 __attribute__((ext_vector_type(4)));

__device__ __constant__ unsigned char c_PI[24] = {0,2,3,4,1,1,1,1,0,0,0,4,4,3,0,2,3,4,2,3,4,2,3,2};
__device__ __constant__ unsigned char c_PJ[24] = {0,2,3,4,0,2,3,4,2,3,4,2,3,2,1,1,1,1,0,0,0,4,4,3};

// per-ROW scratch, shared by the row's 2 waves (h-split). ~6.1 KB -> 12.2 KB/block.
struct __align__(16) RowMem {
  union {
    unsigned hist[256];        // radix-select histogram (single level)
    float Dtab[25 * 33];       // D table [group g][edge m], stride 33 kills 4-way bank conflicts
  } u;
  unsigned long long list[64]; // compacted survivors (unsorted; slot order irrelevant)
  float natoms[KNB * 15];      // neighbor atoms [k][a][xyz]
  float satoms[16];            // self atoms
  float Dn[32];                // D_neighbors (sorted, rank k)
  int   nidx[32];              // neighbor residue index (sorted, rank k)
  int   dk[32];                // positional bucket (sorted, rank k)
  float pmax[2];               // per-wave partial max for Dmax
  unsigned cnt;                // shared survivor counter
  unsigned pad;
};

// distance exactly as numpy: ((dx*dx)+(dy*dy))+(dz*dz), +1e-6, IEEE sqrt, no FMA contraction
__device__ inline float ca_dist(float ax, float ay, float az, float bx, float by, float bz) {
#pragma clang fp contract(off)
  float dx = bx - ax, dy = by - ay, dz = bz - az;
  float d2 = ((dx * dx) + (dy * dy)) + (dz * dz);
  return sqrtf(d2 + 1e-6f);
}

__device__ inline float wmaxf(float v) {
#pragma unroll
  for (int off = 32; off >= 1; off >>= 1) v = fmaxf(v, __shfl_xor(v, off, 64));
  return v;
}

// find smallest bin with cumulative count >= K over 256 bins (4 bins/lane), intra-wave
__device__ inline unsigned scan_find_bin(const unsigned* hist, int lane, unsigned K) {
  uint4 h = ((const uint4*)hist)[lane];
  unsigned p0 = h.x, p1 = p0 + h.y, p2 = p1 + h.z, p3 = p2 + h.w;
  unsigned v = p3;
#pragma unroll
  for (int off = 1; off < 64; off <<= 1) {
    unsigned o = __shfl_up(v, off, 64);
    if (lane >= off) v += o;
  }
  unsigned excl = v - p3;
  unsigned long long bal = __ballot(v >= K);
  int ff = __builtin_ctzll(bal);
  unsigned bi;
  if (excl + p0 >= K)      bi = 0u;
  else if (excl + p1 >= K) bi = 1u;
  else if (excl + p2 >= K) bi = 2u;
  else                     bi = 3u;
  return (unsigned)__shfl((int)(4u * (unsigned)lane + bi), ff, 64);
}

// atom a (0=N,1=Ca,2=C,3=O(slot4),4=Cb) from a 16-float-aligned residue row
__device__ inline void get_atom(const float* __restrict__ base, int a, float& o0, float& o1, float& o2) {
  if (a < 3) {
    o0 = base[a * 3 + 0]; o1 = base[a * 3 + 1]; o2 = base[a * 3 + 2];
  } else if (a == 3) {
    o0 = base[12]; o1 = base[13]; o2 = base[14];
  } else {
    float nx = base[0], ny = base[1], nz = base[2];
    float ax = base[3], ay = base[4], az = base[5];
    float cx = base[6], cy = base[7], cz = base[8];
    float bvx = ax - nx, bvy = ay - ny, bvz = az - nz;
    float cvx = cx - ax, cvy = cy - ay, cvz = cz - az;
    float avx = bvy * cvz - bvz * cvy;
    float avy = bvz * cvx - bvx * cvz;
    float avz = bvx * cvy - bvy * cvx;
    o0 = (-0.58273431f * avx + 0.56802827f * bvx) - 0.54067466f * cvx + ax;
    o1 = (-0.58273431f * avy + 0.56802827f * bvy) - 0.54067466f * cvy + ay;
    o2 = (-0.58273431f * avz + 0.56802827f * bvz) - 0.54067466f * cvz + az;
  }
}

// prep: (1) pre-swizzle edge_W into bf16 B-fragment order
//       (2) repack (Ca.xyz, mask) -> float4 for coalesced distance loads
//       (3) repack 15 atom floats -> 64B-aligned rows (single cacheline per gather)
__global__ void prep(const float* __restrict__ W, __bf16* __restrict__ wf,
                     const float* __restrict__ X, const float* __restrict__ mask,
                     float4* __restrict__ cm, float* __restrict__ x16) {
  int id = blockIdx.x * 256 + threadIdx.x;
  if (id < NWF) {
    int jj = id & 7, l = (id >> 3) & 63, nt = (id >> 9) & 7, s = id >> 12;
    int k = 32 * s + ((l >> 4) << 3) + jj;
    int n = nt * 16 + (l & 15);
    wf[id] = (__bf16)W[n * EDGE_IN + k];
  } else if (id < NWF + NRES) {
    int cid = id - NWF;
    const float* __restrict__ xr = X + (size_t)cid * 15;
    float4 v; v.x = xr[3]; v.y = xr[4]; v.z = xr[5]; v.w = mask[cid];
    cm[cid] = v;
    float4* __restrict__ o = (float4*)(x16 + (size_t)cid * 16);
    o[0] = make_float4(xr[0], xr[1], xr[2], xr[3]);
    o[1] = make_float4(xr[4], xr[5], xr[6], xr[7]);
    o[2] = make_float4(xr[8], xr[9], xr[10], xr[11]);
    o[3] = make_float4(xr[12], xr[13], xr[14], 0.f);
  }
}

// 2 rows/block; each row served by a PAIR of waves (wa=0: edge rows 0-15, wa=1: 16-29).
// Select phase is cooperatively SPLIT across the pair (not duplicated): shared hist,
// shared atomic compact counter, cross-wave max. acc shrinks 64->32 AGPRs so total
// regs/wave ~60 -> reg occupancy cap ~7-8 waves/SIMD (was 4).
__global__ __launch_bounds__(256, 6)
void pf_kernel(const int* __restrict__ ridx, const int* __restrict__ chain,
               const float* __restrict__ posW, const float* __restrict__ posb,
               const float* __restrict__ lng, const float* __restrict__ lnb,
               const __bf16* __restrict__ wf, const float4* __restrict__ cm,
               const float* __restrict__ x16,
               float* __restrict__ outE, float* __restrict__ outI) {
  __shared__ RowMem smr[2];
  const int tid = threadIdx.x, lane = tid & 63, wid = tid >> 6;
  const int rp = wid >> 1, wa = wid & 1;
  RowMem& w = smr[rp];
  const int row = blockIdx.x * 2 + rp;
  const int b = row >> 11;
  const float4* __restrict__ cmb = cm + (size_t)b * LVAL;

  // init shared state (committed by barrier B1)
  if (wa == 0 && lane == 0) w.cnt = 0u;
  { uint2 z = make_uint2(0u, 0u); ((uint2*)w.u.hist)[(wa << 6) | lane] = z; }

  // ---------------- phase 1: distances, 16 candidate chunks per wave ----------------
  float4 me = cm[row];
  const float cax = me.x, cay = me.y, caz = me.z, mi = me.w;

  float Dv[16];
  unsigned mb = 0u;      // bit ql set => candidate masked out
  float lmax = 0.f;
#pragma unroll
  for (int ql = 0; ql < 16; ++ql) {
    int j = ((wa * 16 + ql) << 6) | lane;
    float4 v = cmb[j];
    float m2 = mi * v.w;
    float D = m2 * ca_dist(cax, cay, caz, v.x, v.y, v.z);
    Dv[ql] = D;
    if (m2 == 0.f) mb |= (1u << ql);
    lmax = fmaxf(lmax, D);
  }
  if (lane == 0) w.pmax[wa] = wmaxf(lmax);
  else wmaxf(lmax);
  __syncthreads();                                     // B1: hist zeroed, pmax, cnt
  const float Dmax = fmaxf(w.pmax[0], w.pmax[1]);
  const float fscb = 255.9f / fmaxf(Dmax, 1e-30f);     // Dadj*fscb in [0,255.9)

  // ---------------- radix select: single level, shared 256-bin hist ----------------
#pragma unroll
  for (int ql = 0; ql < 16; ++ql) {
    float Dadj = Dv[ql] + (((mb >> ql) & 1u) ? Dmax : 0.f);
    Dv[ql] = Dadj;                                     // Dv now holds D_adjust
    int bin = min((int)(Dadj * fscb), 255);
    atomicAdd(&w.u.hist[bin], 1u);
  }
  __syncthreads();                                     // B2: hist complete
  const unsigned T1 = scan_find_bin(w.u.hist, lane, 30u);

  // ---------------- compaction: shared atomic counter, slot order irrelevant ----------------
  const unsigned long long lmaskbits = (1ull << lane) - 1ull;
#pragma unroll
  for (int ql = 0; ql < 16; ++ql) {
    int bin = min((int)(Dv[ql] * fscb), 255);
    bool pred = ((unsigned)bin <= T1);
    unsigned long long bal = __ballot(pred);
    unsigned nq = (unsigned)__popcll(bal);
    unsigned base = 0u;
    if (lane == 0) base = atomicAdd(&w.cnt, nq);
    base = (unsigned)__shfl((int)base, 0, 64);
    if (pred) {
      unsigned pos = base + (unsigned)__popcll(bal & lmaskbits);
      if (pos < 64u) {
        unsigned kb = __float_as_uint(Dv[ql]);
        w.list[pos] = (((unsigned long long)kb) << 32) | (unsigned)(((wa * 16 + ql) << 6) | lane);
      }
    }
  }
  __syncthreads();                                     // B3: list + cnt final
  const unsigned M = min(w.cnt, 64u);

  // ---------------- exact rank-sort (both waves redundantly; writes are identical) ----------------
  unsigned long long mykey = (lane < (int)M) ? w.list[lane] : ~0ull;
  unsigned rank = 0;
  for (unsigned s = 0; s < M; ++s) {
    unsigned long long ks = __shfl(mykey, (int)s, 64);
    rank += (ks < mykey) ? 1u : 0u;
  }
  bool sel = (lane < (int)M) && (rank < KNB);
  if (sel) {
    unsigned jj = (unsigned)(mykey & 0xffffffffull);
    w.Dn[rank] = __uint_as_float((unsigned)(mykey >> 32));
    w.nidx[rank] = (int)jj;
    int off = ridx[row] - ridx[b * LVAL + (int)jj];
    int same = (chain[row] == chain[b * LVAL + (int)jj]) ? 1 : 0;
    w.dk[rank] = same ? min(max(off + 32, 0), 64) : 65;
    if (wa == 0) outI[(size_t)row * KNB + rank] = (float)jj;
  }
  __syncthreads();                                     // B4: Dn/nidx/dk ready

  // ---------------- gather atoms: 155 tasks over 128 lanes ----------------
#pragma unroll
  for (int t = 0; t < 2; ++t) {
    int idx = lane + 64 * (wa + 2 * t);                // wa0: 0-63,128-191 ; wa1: 64-127
    if (idx < KNB * 5) {
      int k = idx / 5, a = idx - 5 * k;
      const float* base = x16 + ((size_t)(b * LVAL) + (unsigned)w.nidx[k]) * 16;
      float o0, o1, o2;
      get_atom(base, a, o0, o1, o2);
      w.natoms[k * 15 + a * 3 + 0] = o0;
      w.natoms[k * 15 + a * 3 + 1] = o1;
      w.natoms[k * 15 + a * 3 + 2] = o2;
    } else if (idx < KNB * 5 + 5) {
      int a = idx - KNB * 5;
      float o0, o1, o2;
      get_atom(x16 + (size_t)row * 16, a, o0, o1, o2);
      w.satoms[a * 3 + 0] = o0;
      w.satoms[a * 3 + 1] = o1;
      w.satoms[a * 3 + 2] = o2;
    }
  }
  __syncthreads();                                     // B5: atoms ready

  // ---------------- distance table: Dtab[0][m]=Dn, Dtab[1+p][m]=pair p ----------------
  if (wa == 0 && lane < KNB) w.u.Dtab[lane] = w.Dn[lane];   // hist dead; union reuse
#pragma unroll 1
  for (int t = 0; t < 6; ++t) {
    int idx = (t * 2 + wa) * 64 + lane;                // 128-lane stride over 720 entries
    if (idx < 24 * KNB) {
      int p = idx / KNB, m = idx - KNB * p;
      const float* A = &w.satoms[c_PI[p] * 3];
      const float* Bq = &w.natoms[m * 15 + c_PJ[p] * 3];
      w.u.Dtab[(p + 1) * 33 + m] = ca_dist(A[0], A[1], A[2], Bq[0], Bq[1], Bq[2]);
    }
  }
  __syncthreads();                                     // B6: Dtab ready

  // ---------------- GEMM: this wave owns edge rows h*16..h*16+15, h = wa ----------------
  const int llo = lane & 15, lhi = lane >> 4;
  const int row_e = wa * 16 + llo;
  const bool ok = (row_e < KNB);
  const int re_c = ok ? row_e : 0;
  f32x4 acc[8];
#pragma unroll
  for (int nt = 0; nt < 8; ++nt) { acc[nt][0] = 0.f; acc[nt][1] = 0.f; acc[nt][2] = 0.f; acc[nt][3] = 0.f; }

  const bf16x8* __restrict__ WFp = ((const bf16x8*)wf) + lane;   // + (s*8+nt)*64

#pragma unroll 1
  for (int s = 0; s < 13; ++s) {
    bf16x8 a0;
    const int f0 = s * 32 + lhi * 8;
    if (f0 < 16) {
      // positional-embedding features f0..f0+7 (only s==0, lhi<2)
      int d0 = w.dk[re_c];
#pragma unroll
      for (int jx = 0; jx < 8; ++jx) {
        int f = f0 + jx;
        a0[jx] = ok ? (__bf16)(posW[f * NPOS + d0] + posb[f]) : (__bf16)0.f;
      }
    } else {
      const int gi = (f0 - 16) >> 4;
      const int rbase = (f0 - 16) & 15;              // 0 or 8
      float D0 = ok ? w.u.Dtab[gi * 33 + row_e] : 2.0f;
      const float mu0 = 2.0f + (4.0f / 3.0f) * (float)rbase;
      // e_j = exp(-t_j^2) via geometric recurrence; clamp |t0|<=28 (underflow-safe)
      float t0 = fminf(fmaxf((D0 - mu0) * 0.8f, -28.f), 28.f);
      float e0 = __expf(-t0 * t0);
      float c0 = __expf(2.1333333f * t0 - 1.1377778f);
#pragma unroll
      for (int jx = 0; jx < 8; ++jx) {
        a0[jx] = ok ? (__bf16)e0 : (__bf16)0.f;
        e0 *= c0; c0 *= 0.10273973f;   // exp(-2*(16/15)^2)
      }
    }
    const bf16x8* __restrict__ wrow = WFp + s * 512;
    __builtin_amdgcn_s_setprio(1);
#pragma unroll
    for (int nt = 0; nt < 8; ++nt) {
      bf16x8 bb = wrow[nt * 64];
      acc[nt] = __builtin_amdgcn_mfma_f32_16x16x32_bf16(a0, bb, acc[nt], 0, 0, 0);
    }
    __builtin_amdgcn_s_setprio(0);
  }

  // ---------------- LayerNorm in registers + store (cols intact per wave) ----------------
  float gv[8], bv[8];
#pragma unroll
  for (int nt = 0; nt < 8; ++nt) { gv[nt] = lng[nt * 16 + llo]; bv[nt] = lnb[nt * 16 + llo]; }
  float* __restrict__ oRow = outE + (size_t)row * KNB * NOUT;
#pragma unroll
  for (int r = 0; r < 4; ++r) {
    float s1 = 0.f;
#pragma unroll
    for (int nt = 0; nt < 8; ++nt) s1 += acc[nt][r];
    s1 += __shfl_xor(s1, 1, 64);
    s1 += __shfl_xor(s1, 2, 64);
    s1 += __shfl_xor(s1, 4, 64);
    s1 += __shfl_xor(s1, 8, 64);
    float mu = s1 * (1.0f / 128.0f);
    float s2 = 0.f;
#pragma unroll
    for (int nt = 0; nt < 8; ++nt) { float d = acc[nt][r] - mu; s2 += d * d; }
    s2 += __shfl_xor(s2, 1, 64);
    s2 += __shfl_xor(s2, 2, 64);
    s2 += __shfl_xor(s2, 4, 64);
    s2 += __shfl_xor(s2, 8, 64);
    float rstd = rsqrtf(s2 * (1.0f / 128.0f) + 1e-5f);
    int rowm = wa * 16 + lhi * 4 + r;
    if (rowm < KNB) {
      float* op = oRow + (size_t)rowm * NOUT + llo;
#pragma unroll
      for (int nt = 0; nt < 8; ++nt)
        op[nt * 16] = (acc[nt][r] - mu) * rstd * gv[nt] + bv[nt];
    }
  }
}

extern "C" void kernel_launch(void* const* d_in, const int* in_sizes, int n_in,
                              void* d_out, int out_size, void* d_ws, size_t ws_size,
                              hipStream_t stream) {
  const float* X = (const float*)d_in[0];
  const float* mask = (const float*)d_in[1];
  const int* ridx = (const int*)d_in[2];
  const int* chain = (const int*)d_in[3];
  const float* posW = (const float*)d_in[4];
  const float* posb = (const float*)d_in[5];
  const float* edgeW = (const float*)d_in[6];
  const float* lng = (const float*)d_in[7];
  const float* lnb = (const float*)d_in[8];
  float* outE = (float*)d_out;
  float* outI = outE + (size_t)NRES * KNB * NOUT;

  char* ws = (char*)d_ws;
  __bf16* wf = (__bf16*)ws;                          // 851968 B
  float4* cm = (float4*)(ws + 851968);               // 131072 B  (Ca.xyz, mask)
  float* x16 = (float*)(ws + 851968 + 131072);       // 524288 B  (15 atom floats, 64B rows)

  hipLaunchKernelGGL(prep, dim3((NWF + NRES) / 256), dim3(256), 0, stream,
                     edgeW, wf, X, mask, cm, x16);
  hipLaunchKernelGGL(pf_kernel, dim3(NRES / 2), dim3(256), 0, stream,
                     ridx, chain, posW, posb, lng, lnb, wf, cm, x16, outE, outI);
}

// Round 3
// 217.711 us; speedup vs baseline: 1.0628x; 1.0628x over previous
//
#include <hip/hip_runtime.h>

#define LVAL 2048
#define KNB 30
#define NPOS 66
#define EDGE_IN 416
#define NOUT 128
#define NWF (13 * 8 * 64 * 8)   // 425984 bf16 weight elements (= 851968 B = 53248 float4... /16)
#define NRES (4 * LVAL)         // 8192 residues
#define WF_F4 (NWF * 2 / 16)    // 53248 float4 elements? (NWF*2 bytes /16) = 53248

typedef __bf16 bf16x8 __attribute__((ext_vector_type(8)));
typedef float f32x4 __attribute__((ext_vector_type(4)));

__device__ __constant__ unsigned char c_PI[24] = {0,2,3,4,1,1,1,1,0,0,0,4,4,3,0,2,3,4,2,3,4,2,3,2};
__device__ __constant__ unsigned char c_PJ[24] = {0,2,3,4,0,2,3,4,2,3,4,2,3,2,1,1,1,1,0,0,0,4,4,3};

// Per-wave private scratch. hist -> list -> natoms have strictly sequential
// lifetimes within a wave, so they share one union (saves 1.5 KB/wave; with 16
// waves + full-B in LDS we must fit 160 KB).
struct __align__(16) WS {
  union {
    unsigned hist[256];           // radix-select histogram        (select)
    unsigned long long list[64];  // compacted survivors           (compact/rank-sort)
    float natoms[452];            // neighbor atoms [k][a][xyz]    (gather -> GEMM)
  } u;                            // 1808 B
  float satoms[16];               // self atoms
  float Dn[32];                   // D_neighbors (sorted, rank k)
  int   nidx[32];                 // neighbor residue index (rank k)
  int   dk[32];                   // positional bucket (rank k)
};                                // 2256 B; x16 waves = 36096 B

// distance exactly as numpy: ((dx*dx)+(dy*dy))+(dz*dz), +1e-6, IEEE sqrt, no FMA contraction
__device__ inline float ca_dist(float ax, float ay, float az, float bx, float by, float bz) {
#pragma clang fp contract(off)
  float dx = bx - ax, dy = by - ay, dz = bz - az;
  float d2 = ((dx * dx) + (dy * dy)) + (dz * dz);
  return sqrtf(d2 + 1e-6f);
}

__device__ inline float wmaxf(float v) {
#pragma unroll
  for (int off = 32; off >= 1; off >>= 1) v = fmaxf(v, __shfl_xor(v, off, 64));
  return v;
}

// find smallest bin with cumulative count >= K over 256 bins (4 bins/lane), intra-wave
__device__ inline unsigned scan_find_bin(const unsigned* hist, int lane, unsigned K) {
  uint4 h = ((const uint4*)hist)[lane];
  unsigned p0 = h.x, p1 = p0 + h.y, p2 = p1 + h.z, p3 = p2 + h.w;
  unsigned v = p3;
#pragma unroll
  for (int off = 1; off < 64; off <<= 1) {
    unsigned o = __shfl_up(v, off, 64);
    if (lane >= off) v += o;
  }
  unsigned excl = v - p3;
  unsigned long long bal = __ballot(v >= K);
  int ff = __builtin_ctzll(bal);
  unsigned bi;
  if (excl + p0 >= K)      bi = 0u;
  else if (excl + p1 >= K) bi = 1u;
  else if (excl + p2 >= K) bi = 2u;
  else                     bi = 3u;
  return (unsigned)__shfl((int)(4u * (unsigned)lane + bi), ff, 64);
}

// atom a (0=N,1=Ca,2=C,3=O(slot4),4=Cb) from a 16-float-aligned residue row
__device__ inline void get_atom(const float* __restrict__ base, int a, float& o0, float& o1, float& o2) {
  if (a < 3) {
    o0 = base[a * 3 + 0]; o1 = base[a * 3 + 1]; o2 = base[a * 3 + 2];
  } else if (a == 3) {
    o0 = base[12]; o1 = base[13]; o2 = base[14];
  } else {
    float nx = base[0], ny = base[1], nz = base[2];
    float ax = base[3], ay = base[4], az = base[5];
    float cx = base[6], cy = base[7], cz = base[8];
    float bvx = ax - nx, bvy = ay - ny, bvz = az - nz;
    float cvx = cx - ax, cvy = cy - ay, cvz = cz - az;
    float avx = bvy * cvz - bvz * cvy;
    float avy = bvz * cvx - bvx * cvz;
    float avz = bvx * cvy - bvy * cvx;
    o0 = (-0.58273431f * avx + 0.56802827f * bvx) - 0.54067466f * cvx + ax;
    o1 = (-0.58273431f * avy + 0.56802827f * bvy) - 0.54067466f * cvy + ay;
    o2 = (-0.58273431f * avz + 0.56802827f * bvz) - 0.54067466f * cvz + az;
  }
}

// prep: (1) pre-swizzle edge_W into bf16 B-fragment order
//       (2) repack (Ca.xyz, mask) -> float4 for coalesced distance loads
//       (3) repack 15 atom floats -> 64B-aligned rows (single cacheline per gather)
__global__ void prep(const float* __restrict__ W, __bf16* __restrict__ wf,
                     const float* __restrict__ X, const float* __restrict__ mask,
                     float4* __restrict__ cm, float* __restrict__ x16) {
  int id = blockIdx.x * 256 + threadIdx.x;
  if (id < NWF) {
    int jj = id & 7, l = (id >> 3) & 63, nt = (id >> 9) & 7, s = id >> 12;
    int k = 32 * s + ((l >> 4) << 3) + jj;
    int n = nt * 16 + (l & 15);
    wf[id] = (__bf16)W[n * EDGE_IN + k];
  } else if (id < NWF + NRES) {
    int cid = id - NWF;
    const float* __restrict__ xr = X + (size_t)cid * 15;
    float4 v; v.x = xr[3]; v.y = xr[4]; v.z = xr[5]; v.w = mask[cid];
    cm[cid] = v;
    float4* __restrict__ o = (float4*)(x16 + (size_t)cid * 16);
    o[0] = make_float4(xr[0], xr[1], xr[2], xr[3]);
    o[1] = make_float4(xr[4], xr[5], xr[6], xr[7]);
    o[2] = make_float4(xr[8], xr[9], xr[10], xr[11]);
    o[3] = make_float4(xr[12], xr[13], xr[14], 0.f);
  }
}

// 16 rows/block, 1024 threads (16 waves), 1 wave per row. The ENTIRE 416x128
// bf16 weight matrix (106.5 KB) is staged into LDS once per block; staging
// latency hides under the select phase; exactly ONE __syncthreads in the kernel.
// All B-fragment reads become conflict-free linear ds_read_b128 (no L2 latency
// on the GEMM critical path, 872 MB -> 54 MB of L2 weight traffic).
__global__ __launch_bounds__(1024, 4)
void pf_kernel(const int* __restrict__ ridx, const int* __restrict__ chain,
               const float* __restrict__ posW, const float* __restrict__ posb,
               const float* __restrict__ lng, const float* __restrict__ lnb,
               const __bf16* __restrict__ wf, const float4* __restrict__ cm,
               const float* __restrict__ x16,
               float* __restrict__ outE, float* __restrict__ outI) {
  extern __shared__ char dsm[];                 // 106496 B B-matrix + 16 x WS
  __bf16* ldsB = (__bf16*)dsm;
  WS* wsa = (WS*)(dsm + 106496);

  const int tid = threadIdx.x, lane = tid & 63, wid = tid >> 6;
  WS& w = wsa[wid];
  const int row = blockIdx.x * 16 + wid;        // one wave per row
  const int b = row >> 11;                      // 16-row blocks never cross a batch
  const float4* __restrict__ cmb = cm + (size_t)b * LVAL;

  // ---------------- stage full B into LDS (overlaps with select below) ----------------
  {
    const float4* __restrict__ wf4 = (const float4*)wf;
    float4* ldsB4 = (float4*)ldsB;
#pragma unroll
    for (int t = 0; t < 7; ++t) {
      int idx = t * 1024 + tid;
      if (idx < 6656) ldsB4[idx] = wf4[idx];    // 6656 x 16 B = 106496 B
    }
  }

  // ---------------- phase 1: distances, one coalesced dwordx4 per candidate ----------------
  float4 me = cm[row];
  const float cax = me.x, cay = me.y, caz = me.z, mi = me.w;

  float Dv[32];
  unsigned mb = 0u;      // bit q set => candidate masked out
  float lmax = 0.f;
#pragma unroll
  for (int q = 0; q < 32; ++q) {
    float4 v = cmb[(q << 6) | lane];
    float m2 = mi * v.w;
    float D = m2 * ca_dist(cax, cay, caz, v.x, v.y, v.z);
    Dv[q] = D;
    if (m2 == 0.f) mb |= (1u << q);
    lmax = fmaxf(lmax, D);
  }
  const float Dmax = wmaxf(lmax);
  const float fscb = 255.9f / fmaxf(Dmax, 1e-30f);   // Dadj*fscb in [0,255.9)

  // ---------------- radix select: single level, 256 value-uniform bins ----------------
  { int4 z = {0, 0, 0, 0}; ((int4*)w.u.hist)[lane] = z; }
#pragma unroll
  for (int q = 0; q < 32; ++q) {
    float Dadj = Dv[q] + (((mb >> q) & 1u) ? Dmax : 0.f);
    Dv[q] = Dadj;                                     // Dv now holds D_adjust
    int bin = min((int)(Dadj * fscb), 255);
    atomicAdd(&w.u.hist[bin], 1u);
  }
  const unsigned T1 = scan_find_bin(w.u.hist, lane, 30u);

  // ---------------- compaction (ballot, register-only counter); hist dead, list aliases it ----------------
  unsigned cum = 0;
  const unsigned long long lmaskbits = (1ull << lane) - 1ull;
#pragma unroll
  for (int q = 0; q < 32; ++q) {
    int bin = min((int)(Dv[q] * fscb), 255);
    bool pred = ((unsigned)bin <= T1);
    unsigned long long bal = __ballot(pred);
    if (pred) {
      unsigned pos = cum + (unsigned)__popcll(bal & lmaskbits);
      if (pos < 64u) {
        unsigned kb = __float_as_uint(Dv[q]);
        w.u.list[pos] = (((unsigned long long)kb) << 32) | (unsigned)((q << 6) | lane);
      }
    }
    cum += (unsigned)__popcll(bal);
  }
  const unsigned M = min(cum, 64u);

  // ---------------- exact rank-sort of survivors (keys unique via idx bits) ----------------
  unsigned long long mykey = (lane < (int)M) ? w.u.list[lane] : ~0ull;
  unsigned rank = 0;
  for (unsigned s = 0; s < M; ++s) {
    unsigned long long ks = __shfl(mykey, (int)s, 64);
    rank += (ks < mykey) ? 1u : 0u;
  }
  bool sel = (lane < (int)M) && (rank < KNB);
  if (sel) {
    unsigned jj = (unsigned)(mykey & 0xffffffffull);
    w.Dn[rank] = __uint_as_float((unsigned)(mykey >> 32));
    w.nidx[rank] = (int)jj;
    int off = ridx[row] - ridx[b * LVAL + (int)jj];
    int same = (chain[row] == chain[b * LVAL + (int)jj]) ? 1 : 0;
    w.dk[rank] = same ? min(max(off + 32, 0), 64) : 65;
    outI[(size_t)row * KNB + rank] = (float)jj;
  }

  // ---------------- gather atoms (one 64B line per residue via x16); list dead, natoms aliases ----------------
#pragma unroll
  for (int t = 0; t < 3; ++t) {
    int idx = lane + 64 * t;
    if (idx < KNB * 5) {
      int k = idx / 5, a = idx - 5 * k;
      const float* base = x16 + ((size_t)(b * LVAL) + (unsigned)w.nidx[k]) * 16;
      float o0, o1, o2;
      get_atom(base, a, o0, o1, o2);
      w.u.natoms[k * 15 + a * 3 + 0] = o0;
      w.u.natoms[k * 15 + a * 3 + 1] = o1;
      w.u.natoms[k * 15 + a * 3 + 2] = o2;
    } else if (idx < KNB * 5 + 5) {
      int a = idx - KNB * 5;
      float o0, o1, o2;
      get_atom(x16 + (size_t)row * 16, a, o0, o1, o2);
      w.satoms[a * 3 + 0] = o0;
      w.satoms[a * 3 + 1] = o1;
      w.satoms[a * 3 + 2] = o2;
    }
  }

  __syncthreads();   // B staged by all waves; also all ds_writes above drained

  // ---------------- GEMM from LDS-resident B; pair dists computed on the fly ----------------
  const int llo = lane & 15, lhi = lane >> 4;
  f32x4 acc[2][8];
#pragma unroll
  for (int h = 0; h < 2; ++h)
#pragma unroll
    for (int nt = 0; nt < 8; ++nt) { acc[h][nt][0] = 0.f; acc[h][nt][1] = 0.f; acc[h][nt][2] = 0.f; acc[h][nt][3] = 0.f; }

  const bf16x8* __restrict__ Bf = ((const bf16x8*)ldsB) + lane;  // + (s*8+nt)*64
  const bool m1ok = (llo < 14);                                   // edge llo+16 < 30 ?

#pragma unroll 1
  for (int s = 0; s < 13; ++s) {
    bf16x8 a0, a1;
    const int f0 = s * 32 + lhi * 8;
    if (f0 < 16) {
      // positional-embedding features f0..f0+7 (only s==0, lhi<2)
      int d0 = w.dk[llo];
      int d1 = m1ok ? w.dk[llo + 16] : 0;
#pragma unroll
      for (int jx = 0; jx < 8; ++jx) {
        int f = f0 + jx;
        float pb = posb[f];
        a0[jx] = (__bf16)(posW[f * NPOS + d0] + pb);
        a1[jx] = m1ok ? (__bf16)(posW[f * NPOS + d1] + pb) : (__bf16)0.f;
      }
    } else {
      const int gi = (f0 - 16) >> 4;            // 0 = rbf0 (Dn), 1..24 = pair gi-1
      const int rbase = (f0 - 16) & 15;         // 0 or 8
      float D0, D1;
      if (gi == 0) {
        D0 = w.Dn[llo];
        D1 = m1ok ? w.Dn[llo + 16] : 2.0f;
      } else {
        int p = gi - 1;
        int i3 = c_PI[p] * 3, j3 = c_PJ[p] * 3;
        float ax = w.satoms[i3], ay = w.satoms[i3 + 1], az = w.satoms[i3 + 2];
        const float* nb0 = &w.u.natoms[llo * 15 + j3];
        D0 = ca_dist(ax, ay, az, nb0[0], nb0[1], nb0[2]);
        if (m1ok) {
          const float* nb1 = &w.u.natoms[(llo + 16) * 15 + j3];
          D1 = ca_dist(ax, ay, az, nb1[0], nb1[1], nb1[2]);
        } else D1 = 2.0f;
      }
      const float mu0 = 2.0f + (4.0f / 3.0f) * (float)rbase;
      // e_j = exp(-t_j^2) via geometric recurrence; clamp |t0|<=28 (underflow-safe)
      float t0 = fminf(fmaxf((D0 - mu0) * 0.8f, -28.f), 28.f);
      float t1 = fminf(fmaxf((D1 - mu0) * 0.8f, -28.f), 28.f);
      float e0 = __expf(-t0 * t0);
      float e1 = __expf(-t1 * t1);
      float c0 = __expf(2.1333333f * t0 - 1.1377778f);
      float c1 = __expf(2.1333333f * t1 - 1.1377778f);
#pragma unroll
      for (int jx = 0; jx < 8; ++jx) {
        a0[jx] = (__bf16)e0;
        a1[jx] = m1ok ? (__bf16)e1 : (__bf16)0.f;
        e0 *= c0; c0 *= 0.10273973f;   // exp(-2*(16/15)^2)
        e1 *= c1; c1 *= 0.10273973f;
      }
    }
    const bf16x8* __restrict__ brow = Bf + s * 512;
    __builtin_amdgcn_s_setprio(1);
#pragma unroll
    for (int nt = 0; nt < 8; ++nt) {
      bf16x8 bb = brow[nt * 64];                // linear ds_read_b128
      acc[0][nt] = __builtin_amdgcn_mfma_f32_16x16x32_bf16(a0, bb, acc[0][nt], 0, 0, 0);
      acc[1][nt] = __builtin_amdgcn_mfma_f32_16x16x32_bf16(a1, bb, acc[1][nt], 0, 0, 0);
    }
    __builtin_amdgcn_s_setprio(0);
  }

  // ---------------- LayerNorm in registers + store ----------------
  float gv[8], bv[8];
#pragma unroll
  for (int nt = 0; nt < 8; ++nt) { gv[nt] = lng[nt * 16 + llo]; bv[nt] = lnb[nt * 16 + llo]; }
  float* __restrict__ oRow = outE + (size_t)row * KNB * NOUT;
#pragma unroll
  for (int h = 0; h < 2; ++h) {
#pragma unroll
    for (int r = 0; r < 4; ++r) {
      float s1 = 0.f;
#pragma unroll
      for (int nt = 0; nt < 8; ++nt) s1 += acc[h][nt][r];
      s1 += __shfl_xor(s1, 1, 64);
      s1 += __shfl_xor(s1, 2, 64);
      s1 += __shfl_xor(s1, 4, 64);
      s1 += __shfl_xor(s1, 8, 64);
      float mu = s1 * (1.0f / 128.0f);
      float s2 = 0.f;
#pragma unroll
      for (int nt = 0; nt < 8; ++nt) { float d = acc[h][nt][r] - mu; s2 += d * d; }
      s2 += __shfl_xor(s2, 1, 64);
      s2 += __shfl_xor(s2, 2, 64);
      s2 += __shfl_xor(s2, 4, 64);
      s2 += __shfl_xor(s2, 8, 64);
      float rstd = rsqrtf(s2 * (1.0f / 128.0f) + 1e-5f);
      int rowm = h * 16 + lhi * 4 + r;
      if (rowm < KNB) {
        float* op = oRow + (size_t)rowm * NOUT + llo;
#pragma unroll
        for (int nt = 0; nt < 8; ++nt)
          op[nt * 16] = (acc[h][nt][r] - mu) * rstd * gv[nt] + bv[nt];
      }
    }
  }
}

extern "C" void kernel_launch(void* const* d_in, const int* in_sizes, int n_in,
                              void* d_out, int out_size, void* d_ws, size_t ws_size,
                              hipStream_t stream) {
  const float* X = (const float*)d_in[0];
  const float* mask = (const float*)d_in[1];
  const int* ridx = (const int*)d_in[2];
  const int* chain = (const int*)d_in[3];
  const float* posW = (const float*)d_in[4];
  const float* posb = (const float*)d_in[5];
  const float* edgeW = (const float*)d_in[6];
  const float* lng = (const float*)d_in[7];
  const float* lnb = (const float*)d_in[8];
  float* outE = (float*)d_out;
  float* outI = outE + (size_t)NRES * KNB * NOUT;

  char* ws = (char*)d_ws;
  __bf16* wf = (__bf16*)ws;                          // 851968 B
  float4* cm = (float4*)(ws + 851968);               // 131072 B  (Ca.xyz, mask)
  float* x16 = (float*)(ws + 851968 + 131072);       // 524288 B  (15 atom floats, 64B rows)

  // one-time opt-in for >64KB dynamic LDS (no-op if unnecessary; host-side, capture-safe)
  static bool s_attr = false;
  if (!s_attr) {
    (void)hipFuncSetAttribute((const void*)pf_kernel,
                              hipFuncAttributeMaxDynamicSharedMemorySize, 147456);
    s_attr = true;
  }

  const int ldsBytes = 106496 + 16 * (int)sizeof(WS);   // 106496 + 36096 = 142592

  hipLaunchKernelGGL(prep, dim3((NWF + NRES) / 256), dim3(256), 0, stream,
                     edgeW, wf, X, mask, cm, x16);
  hipLaunchKernelGGL(pf_kernel, dim3(NRES / 16), dim3(1024), ldsBytes, stream,
                     ridx, chain, posW, posb, lng, lnb, wf, cm, x16, outE, outI);
}